// Round 17
// baseline (1719.810 us; speedup 1.0000x reference)
//
#include <hip/hip_runtime.h>

typedef _Float16 h2 __attribute__((ext_vector_type(2)));
union U32H2 { unsigned u; h2 h; };
__device__ __forceinline__ h2 u2h(unsigned u) { U32H2 x; x.u = u; return x.h; }

#if __has_builtin(__builtin_amdgcn_fdot2)
__device__ __forceinline__ float fdot2(h2 a, h2 b, float c) {
  return __builtin_amdgcn_fdot2(a, b, c, false);
}
#else
__device__ __forceinline__ float fdot2(h2 a, h2 b, float c) {
  return c + (float)a[0] * (float)b[0] + (float)a[1] * (float)b[1];
}
#endif

__device__ __forceinline__ unsigned packf16(float a, float b) {
  unsigned short pa = __builtin_bit_cast(unsigned short, (_Float16)a);
  unsigned short pb = __builtin_bit_cast(unsigned short, (_Float16)b);
  return (unsigned)pa | ((unsigned)pb << 16);
}

// ws layout (float offsets):
//   Wcx   [7][2048]       @ 0      fp32 xz-feedback fold
//   WtsT  [21][1024]      @ 14336  fp32: cols 0..13 = (W_out@[W_tr|W_se])^T,
//                                       cols 14..20 = (W_out@[W_tr|W_se]@W_fin)^T
//   bts   [21]+pad        @ 35840
//   WxpP  [512][160] uint @ 35872  f16-pair packed W_xproj (per-step stream)
//   WdtP  [16][1024] uint @ 117792 f16-pair packed W_dt    (per-step stream)
#define WS_WCX  0
#define WS_WTST 14336
#define WS_BTS  35840
#define WS_WXPP 35872
#define WS_WDTP 117792
// total 134176 floats = 536704 B

// ---------------- one-time weight folds + f16 packs ----------------
__global__ __launch_bounds__(256) void k_fold(
    const float* __restrict__ W_feat, const float* __restrict__ W_inproj,
    const float* __restrict__ Wout, const float* __restrict__ Wtr,
    const float* __restrict__ Wse, const float* __restrict__ b_out,
    const float* __restrict__ b_tr, const float* __restrict__ b_se,
    const float* __restrict__ W_fin, const float* __restrict__ b_fin,
    const float* __restrict__ Wxp, const float* __restrict__ Wdt,
    float* __restrict__ ws) {
  const int b = blockIdx.x, t = threadIdx.x;
  unsigned* wsu = reinterpret_cast<unsigned*>(ws);
  if (b < 8) {                       // Wcx[i][j] = sum_k W_feat[512+i][k] W_inproj[k][j]
    int j = b * 256 + t;
    float acc[7] = {0, 0, 0, 0, 0, 0, 0};
    for (int k = 0; k < 512; ++k) {
      float wi = W_inproj[(size_t)k * 2048 + j];
#pragma unroll
      for (int i = 0; i < 7; ++i) acc[i] += W_feat[(size_t)(512 + i) * 512 + k] * wi;
    }
#pragma unroll
    for (int i = 0; i < 7; ++i) ws[WS_WCX + i * 2048 + j] = acc[i];
  } else if (b < 12) {               // WtsT 21 cols (fp32)
    __shared__ float Ush[512][7];    // U[o][c] = [Wtr|Wse][o][:] @ W_fin[:,c]
    for (int o = t; o < 512; o += 256) {
      float u[7] = {0, 0, 0, 0, 0, 0, 0};
#pragma unroll
      for (int j = 0; j < 7; ++j) {
        float a = Wtr[o * 7 + j], bb = Wse[o * 7 + j];
#pragma unroll
        for (int c = 0; c < 7; ++c)
          u[c] += a * W_fin[j * 7 + c] + bb * W_fin[(7 + j) * 7 + c];
      }
#pragma unroll
      for (int c = 0; c < 7; ++c) Ush[o][c] = u[c];
    }
    __syncthreads();
    int k = (b - 8) * 256 + t;
    float acc[21];
#pragma unroll
    for (int c = 0; c < 21; ++c) acc[c] = 0.f;
    const float* wo = Wout + (size_t)k * 512;
    for (int o = 0; o < 512; ++o) {
      float w = wo[o];
      const float* tr = Wtr + o * 7;
      const float* se = Wse + o * 7;
#pragma unroll
      for (int c = 0; c < 7; ++c) {
        acc[c] += w * tr[c]; acc[7 + c] += w * se[c]; acc[14 + c] += w * Ush[o][c];
      }
    }
#pragma unroll
    for (int c = 0; c < 21; ++c) ws[WS_WTST + c * 1024 + k] = acc[c];
  } else if (b == 12) {              // bts[0..13] + folded comb bias [14..20]
    __shared__ float btss[14];
    if (t < 14) {
      int c = (t < 7) ? t : t - 7;
      const float* W = (t < 7) ? Wtr : Wse;
      float s = (t < 7) ? b_tr[t] : b_se[t - 7];
      for (int o = 0; o < 512; ++o) s += b_out[o] * W[o * 7 + c];
      btss[t] = s;
      ws[WS_BTS + t] = s;
    }
    __syncthreads();
    if (t < 7) {
      float s = b_fin[t];
#pragma unroll
      for (int j = 0; j < 14; ++j) s += btss[j] * W_fin[j * 7 + t];
      ws[WS_BTS + 14 + t] = s;
    }
  } else if (b < 333) {              // WxpP: f16 k-pairs
    int idx = (b - 13) * 256 + t;    // [0, 81920)
    int k2 = idx / 160, p = idx - k2 * 160;
    wsu[WS_WXPP + idx] = packf16(Wxp[(size_t)(2 * k2) * 160 + p],
                                 Wxp[(size_t)(2 * k2 + 1) * 160 + p]);
  } else {                           // WdtP: f16 q-pairs
    int idx = (b - 333) * 256 + t;   // [0, 16384)
    int q2 = idx >> 10, o = idx & 1023;
    wsu[WS_WDTP + idx] = packf16(Wdt[(size_t)(2 * q2) * 1024 + o],
                                 Wdt[(size_t)(2 * q2 + 1) * 1024 + o]);
  }
}

// ---------------- persistent scan: 256 blocks x 1024 thr, 4 rows/block ------
struct Pro {                        // prologue-only
  float x2[4][1024];                // 16K
  float hb[4][512];                 // 8K
  float hin[4][512];                // 8K
  float hpart[2][4][512];           // 16K
};
struct Sc {                         // scan-phase
  float4 ycq[1024];                 // 16K  y, quad = 4 rows at one k (Pts input)
  unsigned xchp[512][4];            // 8K   x_c f16 k-pairs, [k2][row] (P2 input)
  float part2[16][4][168];          // 43K
  _Float16 projh[4][32];            // 256B dt_r (f16, P3 input)
  float combs[4][8];
  float bcv[4];
};
union SMem { Pro pro; Sc sc; };

__global__ __launch_bounds__(1024) void k_scan(
    const float* __restrict__ tc, const float* __restrict__ cc,
    const float* __restrict__ initv,
    const float* __restrict__ W_cf, const float* __restrict__ b_cf,
    const float* __restrict__ ln_g, const float* __restrict__ ln_b,
    const float* __restrict__ W_feat, const float* __restrict__ b_feat,
    const float* __restrict__ W_inproj, const float* __restrict__ b_inproj,
    const float* __restrict__ conv_w, const float* __restrict__ conv_b,
    const float* __restrict__ b_dt, const float* __restrict__ D_param,
    const float* __restrict__ ws, float* __restrict__ out) {
  __shared__ SMem S;
  const unsigned* wsu = reinterpret_cast<const unsigned*>(ws);
  const int t = threadIdx.x;          // 0..1023
  const int r0 = blockIdx.x * 4;
  const int o9 = t & 511;
  const int kc9 = t >> 9;

  // ================= prologue =================
  for (int idx = t; idx < 4096; idx += 1024) {
    int r = idx >> 10, k = idx & 1023;
    S.pro.x2[r][k] = (k < 512) ? tc[(size_t)(r0 + r) * 512 + k]
                               : cc[(size_t)(r0 + r) * 512 + (k - 512)];
  }
  __syncthreads();
  // h = relu([tc,cc] @ W_cf + b_cf), K split 2x512
  {
    const float* wp = W_cf + (size_t)(kc9 * 512) * 512 + o9;
    int k0 = kc9 * 512;
    float a0 = 0, a1 = 0, a2 = 0, a3 = 0;
    for (int k = k0; k < k0 + 512; ++k) {
      float w = wp[0]; wp += 512;
      a0 += S.pro.x2[0][k] * w; a1 += S.pro.x2[1][k] * w;
      a2 += S.pro.x2[2][k] * w; a3 += S.pro.x2[3][k] * w;
    }
    S.pro.hpart[kc9][0][o9] = a0; S.pro.hpart[kc9][1][o9] = a1;
    S.pro.hpart[kc9][2][o9] = a2; S.pro.hpart[kc9][3][o9] = a3;
  }
  __syncthreads();
  {
    float b = b_cf[o9];
#pragma unroll
    for (int rr = 0; rr < 2; ++rr) {
      int r = kc9 * 2 + rr;
      S.pro.hb[r][o9] = fmaxf(S.pro.hpart[0][r][o9] + S.pro.hpart[1][r][o9] + b, 0.f);
    }
  }
  __syncthreads();
  // LayerNorm
  if (t < 256) {
    int w = t >> 6, lane = t & 63;
    float s = 0.f, s2 = 0.f;
    for (int j = lane; j < 512; j += 64) { float v = S.pro.hb[w][j]; s += v; s2 += v * v; }
#pragma unroll
    for (int off = 32; off; off >>= 1) { s += __shfl_xor(s, off); s2 += __shfl_xor(s2, off); }
    float mu = s * (1.f / 512.f);
    float var = s2 * (1.f / 512.f) - mu * mu;
    float inv = rsqrtf(var + 1e-5f);
    for (int j = lane; j < 512; j += 64)
      S.pro.hb[w][j] = (S.pro.hb[w][j] - mu) * inv * ln_g[j] + ln_b[j];
  }
  __syncthreads();
  // hin = fused @ W_feat[:512] + b_feat, K split 2x256
  {
    int k0 = kc9 * 256;
    const float* wp = W_feat + (size_t)k0 * 512 + o9;
    float a0 = 0, a1 = 0, a2 = 0, a3 = 0;
    for (int k = k0; k < k0 + 256; ++k) {
      float w = wp[0]; wp += 512;
      a0 += S.pro.hb[0][k] * w; a1 += S.pro.hb[1][k] * w;
      a2 += S.pro.hb[2][k] * w; a3 += S.pro.hb[3][k] * w;
    }
    S.pro.hpart[kc9][0][o9] = a0; S.pro.hpart[kc9][1][o9] = a1;
    S.pro.hpart[kc9][2][o9] = a2; S.pro.hpart[kc9][3][o9] = a3;
  }
  __syncthreads();
  {
    float b = b_feat[o9];
#pragma unroll
    for (int rr = 0; rr < 2; ++rr) {
      int r = kc9 * 2 + rr;
      S.pro.hin[r][o9] = S.pro.hpart[0][r][o9] + S.pro.hpart[1][r][o9] + b;
    }
  }
  __syncthreads();

  // xz_base: thread t owns cols t (x half) and 1024+t (z half), 4 rows
  float xzbx[4], xzbz[4];
#pragma unroll
  for (int half = 0; half < 2; ++half) {
    int col = t + half * 1024;
    const float* wp = W_inproj + col;
    float a0 = 0, a1 = 0, a2 = 0, a3 = 0;
    for (int k = 0; k < 512; ++k) {
      float wi = wp[0]; wp += 2048;
      a0 += S.pro.hin[0][k] * wi; a1 += S.pro.hin[1][k] * wi;
      a2 += S.pro.hin[2][k] * wi; a3 += S.pro.hin[3][k] * wi;
    }
    float bi = b_inproj[col];
    if (half == 0) { xzbx[0] = a0 + bi; xzbx[1] = a1 + bi; xzbx[2] = a2 + bi; xzbx[3] = a3 + bi; }
    else           { xzbz[0] = a0 + bi; xzbz[1] = a1 + bi; xzbz[2] = a2 + bi; xzbz[3] = a3 + bi; }
  }

  // ---- step-invariant per-thread constants (one-time reads) ----
  float wcxx[7], wcxz[7];
#pragma unroll
  for (int i = 0; i < 7; ++i) {
    wcxx[i] = ws[WS_WCX + i * 2048 + t];
    wcxz[i] = ws[WS_WCX + i * 2048 + 1024 + t];
  }
  const float cw3  = conv_w[t * 4 + 3];
  const float cbv  = conv_b[t];
  const float dpar = D_param[t];
  const float bdtv = b_dt[t];
  // Pts weights in registers. Wave wv: colA = wv (ts, wv<14); colB = wv+5 (comb, wv>=9)
  const int wv = t >> 6, ln = t & 63;
  float wtsA[16], btsA = 0.f, wtsB[16], btsB = 0.f;
  if (wv < 14) {
#pragma unroll
    for (int i = 0; i < 16; ++i) wtsA[i] = ws[WS_WTST + wv * 1024 + ln + i * 64];
    btsA = ws[WS_BTS + wv];
  } else {
#pragma unroll
    for (int i = 0; i < 16; ++i) wtsA[i] = 0.f;
  }
  if (wv >= 9) {
#pragma unroll
    for (int i = 0; i < 16; ++i) wtsB[i] = ws[WS_WTST + (wv + 5) * 1024 + ln + i * 64];
    btsB = ws[WS_BTS + wv + 5];
  } else {
#pragma unroll
    for (int i = 0; i < 16; ++i) wtsB[i] = 0.f;
  }

  if (t < 28) S.sc.combs[t / 7][t % 7] = initv[(r0 + t / 7) * 7 + (t % 7)];
  if (t >= 32 && t < 36) S.sc.combs[t - 32][7] = 0.f;   // pad slot for float4 reads
  __syncthreads();

  // ================= 64 sequential decode steps =================
  float zsr[4], xcr[4];
  for (int step = 0; step < 64; ++step) {
    // P1: xz = xz_base + comb @ Wcx; x_c = silu(conv); pack k-pairs across lane
    // pairs (shfl_xor(1)), even lanes store one uint4 covering 4 rows.
    {
      unsigned pk[4];
#pragma unroll
      for (int r = 0; r < 4; ++r) {
        const float4 cA = *reinterpret_cast<const float4*>(&S.sc.combs[r][0]);
        const float4 cB = *reinterpret_cast<const float4*>(&S.sc.combs[r][4]);
        float v = xzbx[r] + cA.x * wcxx[0] + cA.y * wcxx[1] + cA.z * wcxx[2] +
                  cA.w * wcxx[3] + cB.x * wcxx[4] + cB.y * wcxx[5] + cB.z * wcxx[6];
        float u = xzbz[r] + cA.x * wcxz[0] + cA.y * wcxz[1] + cA.z * wcxz[2] +
                  cA.w * wcxz[3] + cB.x * wcxz[4] + cB.y * wcxz[5] + cB.z * wcxz[6];
        v = v * cw3 + cbv;
        float sv = v * __builtin_amdgcn_rcpf(1.f + __expf(-v));
        xcr[r] = sv;
        zsr[r] = u * __builtin_amdgcn_rcpf(1.f + __expf(-u));
        float svo = __shfl_xor(sv, 1);
        pk[r] = packf16(sv, svo);     // valid pairing on even lanes only
      }
      if ((t & 1) == 0)
        *reinterpret_cast<uint4*>(&S.sc.xchp[t >> 1][0]) =
            make_uint4(pk[0], pk[1], pk[2], pk[3]);
    }
    __syncthreads();

    // P2: x_c @ Wxp via f16 dot2. 640 thr = 16 k2-chunks(32) x 40 col-quads.
    // One uint4 weight load (4 cols) + one uint4 x load (4 rows) -> 16 dot2.
    if (t < 640) {
      int kc = t / 40, g = t - kc * 40;     // kc 0..15, g 0..39
      int k2base = kc * 32;
      const uint4* wp = reinterpret_cast<const uint4*>(wsu + WS_WXPP + (size_t)k2base * 160 + 4 * g);
      const uint4* xq = reinterpret_cast<const uint4*>(&S.sc.xchp[k2base][0]);
      float a00 = 0, a01 = 0, a02 = 0, a03 = 0;   // a<col><row>
      float a10 = 0, a11 = 0, a12 = 0, a13 = 0;
      float a20 = 0, a21 = 0, a22 = 0, a23 = 0;
      float a30 = 0, a31 = 0, a32 = 0, a33 = 0;
#pragma unroll 8
      for (int i = 0; i < 32; ++i) {
        uint4 w = wp[(size_t)i * 40];
        uint4 xv = xq[i];
        h2 w0 = u2h(w.x), w1 = u2h(w.y), w2 = u2h(w.z), w3 = u2h(w.w);
        h2 v0 = u2h(xv.x), v1 = u2h(xv.y), v2 = u2h(xv.z), v3 = u2h(xv.w);
        a00 = fdot2(w0, v0, a00); a01 = fdot2(w0, v1, a01);
        a02 = fdot2(w0, v2, a02); a03 = fdot2(w0, v3, a03);
        a10 = fdot2(w1, v0, a10); a11 = fdot2(w1, v1, a11);
        a12 = fdot2(w1, v2, a12); a13 = fdot2(w1, v3, a13);
        a20 = fdot2(w2, v0, a20); a21 = fdot2(w2, v1, a21);
        a22 = fdot2(w2, v2, a22); a23 = fdot2(w2, v3, a23);
        a30 = fdot2(w3, v0, a30); a31 = fdot2(w3, v1, a31);
        a32 = fdot2(w3, v2, a32); a33 = fdot2(w3, v3, a33);
      }
      float4* pr0 = reinterpret_cast<float4*>(&S.sc.part2[kc][0][4 * g]);
      float4* pr1 = reinterpret_cast<float4*>(&S.sc.part2[kc][1][4 * g]);
      float4* pr2 = reinterpret_cast<float4*>(&S.sc.part2[kc][2][4 * g]);
      float4* pr3 = reinterpret_cast<float4*>(&S.sc.part2[kc][3][4 * g]);
      *pr0 = make_float4(a00, a10, a20, a30);
      *pr1 = make_float4(a01, a11, a21, a31);
      *pr2 = make_float4(a02, a12, a22, a32);
      *pr3 = make_float4(a03, a13, a23, a33);
    }
    __syncthreads();

    // reduce dt_r (cols 0..31) -> f16 projh; bc = <Bm,Cm> (cols 32..159)
    if (t < 128) {
      int r = t >> 5, p = t & 31;
      float s = 0.f;
#pragma unroll
      for (int c = 0; c < 16; ++c) s += S.sc.part2[c][r][p];
      S.sc.projh[r][p] = (_Float16)s;
    } else if (t >= 256 && t < 512) {
      int r = (t - 256) >> 6, n = t & 63;
      float bm = 0.f, cm = 0.f;
#pragma unroll
      for (int c = 0; c < 16; ++c) {
        bm += S.sc.part2[c][r][32 + n];
        cm += S.sc.part2[c][r][96 + n];
      }
      float pr = bm * cm;
#pragma unroll
      for (int off = 32; off; off >>= 1) pr += __shfl_xor(pr, off);
      if (n == 0) S.sc.bcv[r] = pr;
    }
    __syncthreads();

    // P3: dt = softplus(dt_r @ W_dt + b_dt) via f16 dot2; y -> float4 ycq[t]
    {
      const unsigned* wp = wsu + WS_WDTP + t;
      const h2* p0 = reinterpret_cast<const h2*>(&S.sc.projh[0][0]);
      const h2* p1 = reinterpret_cast<const h2*>(&S.sc.projh[1][0]);
      const h2* p2 = reinterpret_cast<const h2*>(&S.sc.projh[2][0]);
      const h2* p3 = reinterpret_cast<const h2*>(&S.sc.projh[3][0]);
      float a0 = bdtv, a1 = bdtv, a2 = bdtv, a3 = bdtv;
#pragma unroll
      for (int q2 = 0; q2 < 16; ++q2) {
        h2 wh = u2h(wp[q2 * 1024]);
        a0 = fdot2(wh, p0[q2], a0);
        a1 = fdot2(wh, p1[q2], a1);
        a2 = fdot2(wh, p2[q2], a2);
        a3 = fdot2(wh, p3[q2], a3);
      }
      float y0, y1, y2, y3;
      {
        float v = a0;
        float sp = fmaxf(v, 0.f) + __logf(1.f + __expf(-fabsf(v)));
        y0 = (sp * S.sc.bcv[0] + dpar) * xcr[0] * zsr[0];
      }
      {
        float v = a1;
        float sp = fmaxf(v, 0.f) + __logf(1.f + __expf(-fabsf(v)));
        y1 = (sp * S.sc.bcv[1] + dpar) * xcr[1] * zsr[1];
      }
      {
        float v = a2;
        float sp = fmaxf(v, 0.f) + __logf(1.f + __expf(-fabsf(v)));
        y2 = (sp * S.sc.bcv[2] + dpar) * xcr[2] * zsr[2];
      }
      {
        float v = a3;
        float sp = fmaxf(v, 0.f) + __logf(1.f + __expf(-fabsf(v)));
        y3 = (sp * S.sc.bcv[3] + dpar) * xcr[3] * zsr[3];
      }
      S.sc.ycq[t] = make_float4(y0, y1, y2, y3);
    }
    __syncthreads();

    // Pts: ts/comb = y @ WtsT(21 cols) + bts. One float4 read = 4 rows at k.
    {
      float a0 = 0, a1 = 0, a2 = 0, a3 = 0;
      float b0 = 0, b1 = 0, b2 = 0, b3 = 0;
#pragma unroll
      for (int i = 0; i < 16; ++i) {
        float4 yv = S.sc.ycq[ln + i * 64];
        float wa = wtsA[i], wb = wtsB[i];
        a0 += yv.x * wa; a1 += yv.y * wa; a2 += yv.z * wa; a3 += yv.w * wa;
        b0 += yv.x * wb; b1 += yv.y * wb; b2 += yv.z * wb; b3 += yv.w * wb;
      }
#pragma unroll
      for (int off = 32; off; off >>= 1) {
        a0 += __shfl_xor(a0, off); a1 += __shfl_xor(a1, off);
        a2 += __shfl_xor(a2, off); a3 += __shfl_xor(a3, off);
        b0 += __shfl_xor(b0, off); b1 += __shfl_xor(b1, off);
        b2 += __shfl_xor(b2, off); b3 += __shfl_xor(b3, off);
      }
      if (ln == 0) {
        if (wv < 14) {
          float v0 = a0 + btsA, v1 = a1 + btsA, v2 = a2 + btsA, v3 = a3 + btsA;
          float vals[4] = {v0, v1, v2, v3};
#pragma unroll
          for (int r = 0; r < 4; ++r) {
            size_t idx = ((size_t)(r0 + r) * 64 + step) * 7;
            if (wv < 7) out[idx + wv] = vals[r];
            else out[458752 + idx + (wv - 7)] = vals[r];
          }
        }
        if (wv >= 9) {
          int cc_ = wv - 9;   // comb col 0..6
          float v0 = b0 + btsB, v1 = b1 + btsB, v2 = b2 + btsB, v3 = b3 + btsB;
          float vals[4] = {v0, v1, v2, v3};
#pragma unroll
          for (int r = 0; r < 4; ++r) {
            S.sc.combs[r][cc_] = vals[r];
            out[917504 + ((size_t)(r0 + r) * 64 + step) * 7 + cc_] = vals[r];
          }
        }
      }
    }
    __syncthreads();
  }
}

extern "C" void kernel_launch(void* const* d_in, const int* in_sizes, int n_in,
                              void* d_out, int out_size, void* d_ws, size_t ws_size,
                              hipStream_t stream) {
  const float* tc       = (const float*)d_in[0];
  const float* cc       = (const float*)d_in[1];
  const float* initv    = (const float*)d_in[2];
  const float* W_cf     = (const float*)d_in[3];
  const float* b_cf     = (const float*)d_in[4];
  const float* ln_g     = (const float*)d_in[5];
  const float* ln_b     = (const float*)d_in[6];
  const float* W_feat   = (const float*)d_in[7];
  const float* b_feat   = (const float*)d_in[8];
  const float* W_inproj = (const float*)d_in[9];
  const float* b_inproj = (const float*)d_in[10];
  const float* conv_w   = (const float*)d_in[11];
  const float* conv_b   = (const float*)d_in[12];
  const float* W_xproj  = (const float*)d_in[13];
  const float* W_dt     = (const float*)d_in[14];
  const float* b_dt     = (const float*)d_in[15];
  const float* D_param  = (const float*)d_in[16];
  const float* W_out    = (const float*)d_in[17];
  const float* b_out    = (const float*)d_in[18];
  const float* W_tr     = (const float*)d_in[19];
  const float* b_tr     = (const float*)d_in[20];
  const float* W_se     = (const float*)d_in[21];
  const float* b_se     = (const float*)d_in[22];
  const float* W_fin    = (const float*)d_in[23];
  const float* b_fin    = (const float*)d_in[24];

  float* ws = (float*)d_ws;   // needs 536704 B

  hipLaunchKernelGGL(k_fold, dim3(397), dim3(256), 0, stream,
                     W_feat, W_inproj, W_out, W_tr, W_se, b_out, b_tr, b_se,
                     W_fin, b_fin, W_xproj, W_dt, ws);
  hipLaunchKernelGGL(k_scan, dim3(256), dim3(1024), 0, stream,
                     tc, cc, initv, W_cf, b_cf, ln_g, ln_b, W_feat, b_feat,
                     W_inproj, b_inproj, conv_w, conv_b, b_dt, D_param,
                     ws, (float*)d_out);
}

// Round 18
// 1379.134 us; speedup vs baseline: 1.2470x; 1.2470x over previous
//
#include <hip/hip_runtime.h>

typedef _Float16 h2 __attribute__((ext_vector_type(2)));
union U32H2 { unsigned u; h2 h; };
__device__ __forceinline__ h2 u2h(unsigned u) { U32H2 x; x.u = u; return x.h; }

#if __has_builtin(__builtin_amdgcn_fdot2)
__device__ __forceinline__ float fdot2(h2 a, h2 b, float c) {
  return __builtin_amdgcn_fdot2(a, b, c, false);
}
#else
__device__ __forceinline__ float fdot2(h2 a, h2 b, float c) {
  return c + (float)a[0] * (float)b[0] + (float)a[1] * (float)b[1];
}
#endif

__device__ __forceinline__ unsigned packf16(float a, float b) {
  unsigned short pa = __builtin_bit_cast(unsigned short, (_Float16)a);
  unsigned short pb = __builtin_bit_cast(unsigned short, (_Float16)b);
  return (unsigned)pa | ((unsigned)pb << 16);
}

// ws layout (float offsets):
//   Wcx   [7][2048]       @ 0       fp32 xz-feedback fold
//   WtsT  [21][1024]      @ 14336   fp32: cols 0..13 = (W_out@[W_tr|W_se])^T,
//                                        cols 14..20 = (W_out@[W_tr|W_se]@W_fin)^T
//   bts   [21]+pad        @ 35840   matching biases
//   WxpP  [512][160] uint @ 35872   f16-pair packed W_xproj (per-step stream)
//   WdtP  [16][1024] uint @ 117792  f16-pair packed W_dt    (per-step stream)
#define WS_WCX  0
#define WS_WTST 14336
#define WS_BTS  35840
#define WS_WXPP 35872
#define WS_WDTP 117792
// total 134176 floats = 536704 B

// ---------------- one-time weight folds + f16 packs ----------------
__global__ __launch_bounds__(256) void k_fold(
    const float* __restrict__ W_feat, const float* __restrict__ W_inproj,
    const float* __restrict__ Wout, const float* __restrict__ Wtr,
    const float* __restrict__ Wse, const float* __restrict__ b_out,
    const float* __restrict__ b_tr, const float* __restrict__ b_se,
    const float* __restrict__ W_fin, const float* __restrict__ b_fin,
    const float* __restrict__ Wxp, const float* __restrict__ Wdt,
    float* __restrict__ ws) {
  const int b = blockIdx.x, t = threadIdx.x;
  unsigned* wsu = reinterpret_cast<unsigned*>(ws);
  if (b < 8) {                       // Wcx[i][j] = sum_k W_feat[512+i][k] W_inproj[k][j]
    int j = b * 256 + t;
    float acc[7] = {0, 0, 0, 0, 0, 0, 0};
    for (int k = 0; k < 512; ++k) {
      float wi = W_inproj[(size_t)k * 2048 + j];
#pragma unroll
      for (int i = 0; i < 7; ++i) acc[i] += W_feat[(size_t)(512 + i) * 512 + k] * wi;
    }
#pragma unroll
    for (int i = 0; i < 7; ++i) ws[WS_WCX + i * 2048 + j] = acc[i];
  } else if (b < 12) {               // WtsT 21 cols
    __shared__ float Ush[512][7];    // U[o][c] = sum_j [Wtr|Wse][o][j] * W_fin[j][c]
    for (int o = t; o < 512; o += 256) {
      float u[7] = {0, 0, 0, 0, 0, 0, 0};
#pragma unroll
      for (int j = 0; j < 7; ++j) {
        float a = Wtr[o * 7 + j], bb = Wse[o * 7 + j];
#pragma unroll
        for (int c = 0; c < 7; ++c)
          u[c] += a * W_fin[j * 7 + c] + bb * W_fin[(7 + j) * 7 + c];
      }
#pragma unroll
      for (int c = 0; c < 7; ++c) Ush[o][c] = u[c];
    }
    __syncthreads();
    int k = (b - 8) * 256 + t;
    float acc[21];
#pragma unroll
    for (int c = 0; c < 21; ++c) acc[c] = 0.f;
    const float* wo = Wout + (size_t)k * 512;
    for (int o = 0; o < 512; ++o) {
      float w = wo[o];
      const float* tr = Wtr + o * 7;
      const float* se = Wse + o * 7;
#pragma unroll
      for (int c = 0; c < 7; ++c) {
        acc[c] += w * tr[c]; acc[7 + c] += w * se[c]; acc[14 + c] += w * Ush[o][c];
      }
    }
#pragma unroll
    for (int c = 0; c < 21; ++c) ws[WS_WTST + c * 1024 + k] = acc[c];
  } else if (b == 12) {              // bts[0..13], btsc[14..20]
    __shared__ float btss[14];
    if (t < 14) {
      int c = (t < 7) ? t : t - 7;
      const float* W = (t < 7) ? Wtr : Wse;
      float s = (t < 7) ? b_tr[t] : b_se[t - 7];
      for (int o = 0; o < 512; ++o) s += b_out[o] * W[o * 7 + c];
      btss[t] = s;
      ws[WS_BTS + t] = s;
    }
    __syncthreads();
    if (t < 7) {
      float s = b_fin[t];
#pragma unroll
      for (int j = 0; j < 14; ++j) s += btss[j] * W_fin[j * 7 + t];
      ws[WS_BTS + 14 + t] = s;
    }
  } else if (b < 333) {              // WxpP: f16 k-pairs
    int idx = (b - 13) * 256 + t;    // [0, 81920)
    int k2 = idx / 160, p = idx - k2 * 160;
    wsu[WS_WXPP + idx] = packf16(Wxp[(size_t)(2 * k2) * 160 + p],
                                 Wxp[(size_t)(2 * k2 + 1) * 160 + p]);
  } else {                           // WdtP: f16 q-pairs
    int idx = (b - 333) * 256 + t;   // [0, 16384)
    int q2 = idx >> 10, o = idx & 1023;
    wsu[WS_WDTP + idx] = packf16(Wdt[(size_t)(2 * q2) * 1024 + o],
                                 Wdt[(size_t)(2 * q2 + 1) * 1024 + o]);
  }
}

// ---------------- persistent scan: 256 blocks x 1024 thr, 4 rows/block ------
struct Pro {                        // prologue-only
  float x2[4][1024];                // 16K
  float hb[4][512];                 // 8K
  float hin[4][512];                // 8K
  float hpart[2][4][512];           // 16K
};
struct Sc {                         // scan-phase
  float xc[4][1024];                // 16K  y (f32, Pts input)
  _Float16 xch[4][1024];            // 8K   x_c (f16, P2 input)
  float part2[16][4][168];          // 43K
  _Float16 projh[4][32];            // 256B dt_r (f16, P3 input)
  float combs[4][8];
  float bcv[4];
};
union SMem { Pro pro; Sc sc; };

__global__ __launch_bounds__(1024) void k_scan(
    const float* __restrict__ tc, const float* __restrict__ cc,
    const float* __restrict__ initv,
    const float* __restrict__ W_cf, const float* __restrict__ b_cf,
    const float* __restrict__ ln_g, const float* __restrict__ ln_b,
    const float* __restrict__ W_feat, const float* __restrict__ b_feat,
    const float* __restrict__ W_inproj, const float* __restrict__ b_inproj,
    const float* __restrict__ conv_w, const float* __restrict__ conv_b,
    const float* __restrict__ b_dt, const float* __restrict__ D_param,
    const float* __restrict__ ws, float* __restrict__ out) {
  __shared__ SMem S;
  const unsigned* wsu = reinterpret_cast<const unsigned*>(ws);
  const int t = threadIdx.x;          // 0..1023
  const int r0 = blockIdx.x * 4;
  const int o9 = t & 511;
  const int kc9 = t >> 9;

  // ================= prologue =================
  for (int idx = t; idx < 4096; idx += 1024) {
    int r = idx >> 10, k = idx & 1023;
    S.pro.x2[r][k] = (k < 512) ? tc[(size_t)(r0 + r) * 512 + k]
                               : cc[(size_t)(r0 + r) * 512 + (k - 512)];
  }
  __syncthreads();
  // h = relu([tc,cc] @ W_cf + b_cf), K split 2x512
  {
    const float* wp = W_cf + (size_t)(kc9 * 512) * 512 + o9;
    int k0 = kc9 * 512;
    float a0 = 0, a1 = 0, a2 = 0, a3 = 0;
    for (int k = k0; k < k0 + 512; ++k) {
      float w = wp[0]; wp += 512;
      a0 += S.pro.x2[0][k] * w; a1 += S.pro.x2[1][k] * w;
      a2 += S.pro.x2[2][k] * w; a3 += S.pro.x2[3][k] * w;
    }
    S.pro.hpart[kc9][0][o9] = a0; S.pro.hpart[kc9][1][o9] = a1;
    S.pro.hpart[kc9][2][o9] = a2; S.pro.hpart[kc9][3][o9] = a3;
  }
  __syncthreads();
  {
    float b = b_cf[o9];
#pragma unroll
    for (int rr = 0; rr < 2; ++rr) {
      int r = kc9 * 2 + rr;
      S.pro.hb[r][o9] = fmaxf(S.pro.hpart[0][r][o9] + S.pro.hpart[1][r][o9] + b, 0.f);
    }
  }
  __syncthreads();
  // LayerNorm
  if (t < 256) {
    int w = t >> 6, lane = t & 63;
    float s = 0.f, s2 = 0.f;
    for (int j = lane; j < 512; j += 64) { float v = S.pro.hb[w][j]; s += v; s2 += v * v; }
#pragma unroll
    for (int off = 32; off; off >>= 1) { s += __shfl_xor(s, off); s2 += __shfl_xor(s2, off); }
    float mu = s * (1.f / 512.f);
    float var = s2 * (1.f / 512.f) - mu * mu;
    float inv = rsqrtf(var + 1e-5f);
    for (int j = lane; j < 512; j += 64)
      S.pro.hb[w][j] = (S.pro.hb[w][j] - mu) * inv * ln_g[j] + ln_b[j];
  }
  __syncthreads();
  // hin = fused @ W_feat[:512] + b_feat, K split 2x256
  {
    int k0 = kc9 * 256;
    const float* wp = W_feat + (size_t)k0 * 512 + o9;
    float a0 = 0, a1 = 0, a2 = 0, a3 = 0;
    for (int k = k0; k < k0 + 256; ++k) {
      float w = wp[0]; wp += 512;
      a0 += S.pro.hb[0][k] * w; a1 += S.pro.hb[1][k] * w;
      a2 += S.pro.hb[2][k] * w; a3 += S.pro.hb[3][k] * w;
    }
    S.pro.hpart[kc9][0][o9] = a0; S.pro.hpart[kc9][1][o9] = a1;
    S.pro.hpart[kc9][2][o9] = a2; S.pro.hpart[kc9][3][o9] = a3;
  }
  __syncthreads();
  {
    float b = b_feat[o9];
#pragma unroll
    for (int rr = 0; rr < 2; ++rr) {
      int r = kc9 * 2 + rr;
      S.pro.hin[r][o9] = S.pro.hpart[0][r][o9] + S.pro.hpart[1][r][o9] + b;
    }
  }
  __syncthreads();

  // xz_base: thread t owns cols t (x half) and 1024+t (z half), 4 rows
  float xzbx[4], xzbz[4];
#pragma unroll
  for (int half = 0; half < 2; ++half) {
    int col = t + half * 1024;
    const float* wp = W_inproj + col;
    float a0 = 0, a1 = 0, a2 = 0, a3 = 0;
    for (int k = 0; k < 512; ++k) {
      float wi = wp[0]; wp += 2048;
      a0 += S.pro.hin[0][k] * wi; a1 += S.pro.hin[1][k] * wi;
      a2 += S.pro.hin[2][k] * wi; a3 += S.pro.hin[3][k] * wi;
    }
    float bi = b_inproj[col];
    if (half == 0) { xzbx[0] = a0 + bi; xzbx[1] = a1 + bi; xzbx[2] = a2 + bi; xzbx[3] = a3 + bi; }
    else           { xzbz[0] = a0 + bi; xzbz[1] = a1 + bi; xzbz[2] = a2 + bi; xzbz[3] = a3 + bi; }
  }

  // ---- step-invariant per-thread constants (one-time reads) ----
  float wcxx[7], wcxz[7];
#pragma unroll
  for (int i = 0; i < 7; ++i) {
    wcxx[i] = ws[WS_WCX + i * 2048 + t];
    wcxz[i] = ws[WS_WCX + i * 2048 + 1024 + t];
  }
  const float cw3  = conv_w[t * 4 + 3];
  const float cbv  = conv_b[t];
  const float dpar = D_param[t];
  const float bdtv = b_dt[t];
  // Pts weights in registers. Wave wv: colA = wv (ts, wv<14); colB = wv+5 (comb, wv>=9)
  const int wv = t >> 6, ln = t & 63;
  float wtsA[16], btsA = 0.f, wtsB[16], btsB = 0.f;
  if (wv < 14) {
#pragma unroll
    for (int i = 0; i < 16; ++i) wtsA[i] = ws[WS_WTST + wv * 1024 + ln + i * 64];
    btsA = ws[WS_BTS + wv];
  } else {
#pragma unroll
    for (int i = 0; i < 16; ++i) wtsA[i] = 0.f;
  }
  if (wv >= 9) {
#pragma unroll
    for (int i = 0; i < 16; ++i) wtsB[i] = ws[WS_WTST + (wv + 5) * 1024 + ln + i * 64];
    btsB = ws[WS_BTS + wv + 5];
  } else {
#pragma unroll
    for (int i = 0; i < 16; ++i) wtsB[i] = 0.f;
  }

  if (t < 28) S.sc.combs[t / 7][t % 7] = initv[(r0 + t / 7) * 7 + (t % 7)];
  __syncthreads();

  // ================= 64 sequential decode steps =================
  float zsr[4], xcr[4];
  for (int step = 0; step < 64; ++step) {
    // P1: xz = xz_base + comb @ Wcx; x_c = silu(conv) -> f16 LDS + reg; silu(z) -> reg
#pragma unroll
    for (int r = 0; r < 4; ++r) {
      float v = xzbx[r], u = xzbz[r];
#pragma unroll
      for (int i = 0; i < 7; ++i) {
        float cb_ = S.sc.combs[r][i];
        v += cb_ * wcxx[i];
        u += cb_ * wcxz[i];
      }
      v = v * cw3 + cbv;
      float sv = v / (1.f + __expf(-v));
      xcr[r] = sv;
      S.sc.xch[r][t] = (_Float16)sv;
      zsr[r] = u / (1.f + __expf(-u));
    }
    __syncthreads();

    // P2: x_c @ Wxp via f16 dot2. 640 thr = 16 k2-chunks(32) x 40 col-quads.
    if (t < 640) {
      int kc = t / 40, g = t - kc * 40;     // kc 0..15, g 0..39
      int k2base = kc * 32, kbase = kc * 64;
      const uint4* wp = reinterpret_cast<const uint4*>(wsu + WS_WXPP + (size_t)k2base * 160 + 4 * g);
      const h2* x0 = reinterpret_cast<const h2*>(&S.sc.xch[0][kbase]);
      const h2* x1 = reinterpret_cast<const h2*>(&S.sc.xch[1][kbase]);
      const h2* x2 = reinterpret_cast<const h2*>(&S.sc.xch[2][kbase]);
      const h2* x3 = reinterpret_cast<const h2*>(&S.sc.xch[3][kbase]);
      float a00 = 0, a01 = 0, a02 = 0, a03 = 0;   // a<col><row>
      float a10 = 0, a11 = 0, a12 = 0, a13 = 0;
      float a20 = 0, a21 = 0, a22 = 0, a23 = 0;
      float a30 = 0, a31 = 0, a32 = 0, a33 = 0;
#pragma unroll 8
      for (int i = 0; i < 32; ++i) {
        uint4 w = wp[(size_t)i * 40];
        h2 w0 = u2h(w.x), w1 = u2h(w.y), w2 = u2h(w.z), w3 = u2h(w.w);
        h2 v0 = x0[i], v1 = x1[i], v2 = x2[i], v3 = x3[i];
        a00 = fdot2(w0, v0, a00); a01 = fdot2(w0, v1, a01);
        a02 = fdot2(w0, v2, a02); a03 = fdot2(w0, v3, a03);
        a10 = fdot2(w1, v0, a10); a11 = fdot2(w1, v1, a11);
        a12 = fdot2(w1, v2, a12); a13 = fdot2(w1, v3, a13);
        a20 = fdot2(w2, v0, a20); a21 = fdot2(w2, v1, a21);
        a22 = fdot2(w2, v2, a22); a23 = fdot2(w2, v3, a23);
        a30 = fdot2(w3, v0, a30); a31 = fdot2(w3, v1, a31);
        a32 = fdot2(w3, v2, a32); a33 = fdot2(w3, v3, a33);
      }
      float4* pr0 = reinterpret_cast<float4*>(&S.sc.part2[kc][0][4 * g]);
      float4* pr1 = reinterpret_cast<float4*>(&S.sc.part2[kc][1][4 * g]);
      float4* pr2 = reinterpret_cast<float4*>(&S.sc.part2[kc][2][4 * g]);
      float4* pr3 = reinterpret_cast<float4*>(&S.sc.part2[kc][3][4 * g]);
      *pr0 = make_float4(a00, a10, a20, a30);
      *pr1 = make_float4(a01, a11, a21, a31);
      *pr2 = make_float4(a02, a12, a22, a32);
      *pr3 = make_float4(a03, a13, a23, a33);
    }
    __syncthreads();

    // reduce dt_r (cols 0..31) -> f16 projh; bc = <Bm,Cm> (cols 32..159)
    if (t < 128) {
      int r = t >> 5, p = t & 31;
      float s = 0.f;
#pragma unroll
      for (int c = 0; c < 16; ++c) s += S.sc.part2[c][r][p];
      S.sc.projh[r][p] = (_Float16)s;
    } else if (t >= 256 && t < 512) {
      int r = (t - 256) >> 6, n = t & 63;
      float bm = 0.f, cm = 0.f;
#pragma unroll
      for (int c = 0; c < 16; ++c) {
        bm += S.sc.part2[c][r][32 + n];
        cm += S.sc.part2[c][r][96 + n];
      }
      float pr = bm * cm;
#pragma unroll
      for (int off = 32; off; off >>= 1) pr += __shfl_xor(pr, off);
      if (n == 0) S.sc.bcv[r] = pr;
    }
    __syncthreads();

    // P3: dt = softplus(dt_r @ W_dt + b_dt) via f16 dot2; y -> f32 xc
    {
      const unsigned* wp = wsu + WS_WDTP + t;
      const h2* p0 = reinterpret_cast<const h2*>(&S.sc.projh[0][0]);
      const h2* p1 = reinterpret_cast<const h2*>(&S.sc.projh[1][0]);
      const h2* p2 = reinterpret_cast<const h2*>(&S.sc.projh[2][0]);
      const h2* p3 = reinterpret_cast<const h2*>(&S.sc.projh[3][0]);
      float a0 = bdtv, a1 = bdtv, a2 = bdtv, a3 = bdtv;
#pragma unroll
      for (int q2 = 0; q2 < 16; ++q2) {
        h2 wh = u2h(wp[q2 * 1024]);
        a0 = fdot2(wh, p0[q2], a0);
        a1 = fdot2(wh, p1[q2], a1);
        a2 = fdot2(wh, p2[q2], a2);
        a3 = fdot2(wh, p3[q2], a3);
      }
      float accs[4] = {a0, a1, a2, a3};
#pragma unroll
      for (int r = 0; r < 4; ++r) {
        float v = accs[r];
        float sp = fmaxf(v, 0.f) + log1pf(__expf(-fabsf(v)));
        S.sc.xc[r][t] = (sp * S.sc.bcv[r] + dpar) * xcr[r] * zsr[r];
      }
    }
    __syncthreads();

    // Pts: ts/comb = y @ WtsT(21 cols) + bts. colA = wv (ts), colB = wv+5 (comb).
    {
      float a0 = 0, a1 = 0, a2 = 0, a3 = 0;
      float b0 = 0, b1 = 0, b2 = 0, b3 = 0;
#pragma unroll
      for (int i = 0; i < 16; ++i) {
        int k = ln + i * 64;
        float y0 = S.sc.xc[0][k], y1 = S.sc.xc[1][k];
        float y2 = S.sc.xc[2][k], y3 = S.sc.xc[3][k];
        float wa = wtsA[i], wb = wtsB[i];
        a0 += y0 * wa; a1 += y1 * wa; a2 += y2 * wa; a3 += y3 * wa;
        b0 += y0 * wb; b1 += y1 * wb; b2 += y2 * wb; b3 += y3 * wb;
      }
#pragma unroll
      for (int off = 32; off; off >>= 1) {
        a0 += __shfl_xor(a0, off); a1 += __shfl_xor(a1, off);
        a2 += __shfl_xor(a2, off); a3 += __shfl_xor(a3, off);
        b0 += __shfl_xor(b0, off); b1 += __shfl_xor(b1, off);
        b2 += __shfl_xor(b2, off); b3 += __shfl_xor(b3, off);
      }
      if (ln == 0) {
        if (wv < 14) {
          float v0 = a0 + btsA, v1 = a1 + btsA, v2 = a2 + btsA, v3 = a3 + btsA;
          float vals[4] = {v0, v1, v2, v3};
#pragma unroll
          for (int r = 0; r < 4; ++r) {
            size_t idx = ((size_t)(r0 + r) * 64 + step) * 7;
            if (wv < 7) out[idx + wv] = vals[r];
            else out[458752 + idx + (wv - 7)] = vals[r];
          }
        }
        if (wv >= 9) {
          int cc_ = wv - 9;   // comb col 0..6
          float v0 = b0 + btsB, v1 = b1 + btsB, v2 = b2 + btsB, v3 = b3 + btsB;
          float vals[4] = {v0, v1, v2, v3};
#pragma unroll
          for (int r = 0; r < 4; ++r) {
            S.sc.combs[r][cc_] = vals[r];
            out[917504 + ((size_t)(r0 + r) * 64 + step) * 7 + cc_] = vals[r];
          }
        }
      }
    }
    __syncthreads();
  }
}

extern "C" void kernel_launch(void* const* d_in, const int* in_sizes, int n_in,
                              void* d_out, int out_size, void* d_ws, size_t ws_size,
                              hipStream_t stream) {
  const float* tc       = (const float*)d_in[0];
  const float* cc       = (const float*)d_in[1];
  const float* initv    = (const float*)d_in[2];
  const float* W_cf     = (const float*)d_in[3];
  const float* b_cf     = (const float*)d_in[4];
  const float* ln_g     = (const float*)d_in[5];
  const float* ln_b     = (const float*)d_in[6];
  const float* W_feat   = (const float*)d_in[7];
  const float* b_feat   = (const float*)d_in[8];
  const float* W_inproj = (const float*)d_in[9];
  const float* b_inproj = (const float*)d_in[10];
  const float* conv_w   = (const float*)d_in[11];
  const float* conv_b   = (const float*)d_in[12];
  const float* W_xproj  = (const float*)d_in[13];
  const float* W_dt     = (const float*)d_in[14];
  const float* b_dt     = (const float*)d_in[15];
  const float* D_param  = (const float*)d_in[16];
  const float* W_out    = (const float*)d_in[17];
  const float* b_out    = (const float*)d_in[18];
  const float* W_tr     = (const float*)d_in[19];
  const float* b_tr     = (const float*)d_in[20];
  const float* W_se     = (const float*)d_in[21];
  const float* b_se     = (const float*)d_in[22];
  const float* W_fin    = (const float*)d_in[23];
  const float* b_fin    = (const float*)d_in[24];

  float* ws = (float*)d_ws;   // needs 536704 B

  hipLaunchKernelGGL(k_fold, dim3(397), dim3(256), 0, stream,
                     W_feat, W_inproj, W_out, W_tr, W_se, b_out, b_tr, b_se,
                     W_fin, b_fin, W_xproj, W_dt, ws);
  hipLaunchKernelGGL(k_scan, dim3(256), dim3(1024), 0, stream,
                     tc, cc, initv, W_cf, b_cf, ln_g, ln_b, W_feat, b_feat,
                     W_inproj, b_inproj, conv_w, conv_b, b_dt, D_param,
                     ws, (float*)d_out);
}